// Round 1
// baseline (322802.173 us; speedup 1.0000x reference)
//
#include <hip/hip_runtime.h>

// ReverseLSTMLayer: T=1024, B=32, I=1024, H=1024, fp32.
// outputs[t] = h at step t, iterating t = T-1 .. 0 (reverse scan).
// d_out layout: outputs [T*B*H] | h_fin [B*H] | c_fin [B*H].

constexpr int T_STEPS = 1024;
constexpr int BATCH   = 32;
constexpr int IN_DIM  = 1024;
constexpr int HID     = 1024;

// Fused LSTM cell step: each thread owns one (b, j) column and computes all
// 4 gate dot-products (K = IN_DIM for x-part + HID for h-part), then the
// pointwise cell update. Grid = BATCH * (HID/256) = 128 blocks, 256 threads.
__global__ __launch_bounds__(256) void lstm_step_fused(
    const float* __restrict__ x_t,     // [B, I] slice of input at step t
    const float* __restrict__ h_prev,  // [B, H]
    const float* __restrict__ c_prev,  // [B, H]
    float* __restrict__ c_out,         // [B, H] (ws)
    float* __restrict__ h_out,         // [B, H] (= out + t*B*H)
    const float* __restrict__ W_ih,    // [4H, I]
    const float* __restrict__ W_hh,    // [4H, H]
    const float* __restrict__ b_ih,    // [4H]
    const float* __restrict__ b_hh)    // [4H]
{
    __shared__ float xs[IN_DIM];
    __shared__ float hs[HID];
    const int tid = threadIdx.x;
    const int b   = blockIdx.x >> 2;                  // 32 batches
    const int j   = ((blockIdx.x & 3) << 8) | tid;    // 0..1023 column

    // Cooperative stage of x_t[b,:] and h_prev[b,:] into LDS (float4).
    ((float4*)xs)[tid] = ((const float4*)(x_t    + (size_t)b * IN_DIM))[tid];
    ((float4*)hs)[tid] = ((const float4*)(h_prev + (size_t)b * HID))[tid];
    __syncthreads();

    float a0 = b_ih[j]         + b_hh[j];           // i
    float a1 = b_ih[HID + j]   + b_hh[HID + j];     // f
    float a2 = b_ih[2*HID + j] + b_hh[2*HID + j];   // g
    float a3 = b_ih[3*HID + j] + b_hh[3*HID + j];   // o

    // x-part: gates += x_t[b,:] . W_ih[g*H+j, :]
    {
        const float4* wi0 = (const float4*)(W_ih + (size_t)(0*HID + j) * IN_DIM);
        const float4* wi1 = (const float4*)(W_ih + (size_t)(1*HID + j) * IN_DIM);
        const float4* wi2 = (const float4*)(W_ih + (size_t)(2*HID + j) * IN_DIM);
        const float4* wi3 = (const float4*)(W_ih + (size_t)(3*HID + j) * IN_DIM);
        const float4* xs4 = (const float4*)xs;
        #pragma unroll 4
        for (int k = 0; k < IN_DIM / 4; ++k) {
            const float4 xv = xs4[k];
            float4 w;
            w = wi0[k]; a0 += xv.x*w.x + xv.y*w.y + xv.z*w.z + xv.w*w.w;
            w = wi1[k]; a1 += xv.x*w.x + xv.y*w.y + xv.z*w.z + xv.w*w.w;
            w = wi2[k]; a2 += xv.x*w.x + xv.y*w.y + xv.z*w.z + xv.w*w.w;
            w = wi3[k]; a3 += xv.x*w.x + xv.y*w.y + xv.z*w.z + xv.w*w.w;
        }
    }
    // h-part: gates += h_prev[b,:] . W_hh[g*H+j, :]
    {
        const float4* wh0 = (const float4*)(W_hh + (size_t)(0*HID + j) * HID);
        const float4* wh1 = (const float4*)(W_hh + (size_t)(1*HID + j) * HID);
        const float4* wh2 = (const float4*)(W_hh + (size_t)(2*HID + j) * HID);
        const float4* wh3 = (const float4*)(W_hh + (size_t)(3*HID + j) * HID);
        const float4* hs4 = (const float4*)hs;
        #pragma unroll 4
        for (int k = 0; k < HID / 4; ++k) {
            const float4 hv = hs4[k];
            float4 w;
            w = wh0[k]; a0 += hv.x*w.x + hv.y*w.y + hv.z*w.z + hv.w*w.w;
            w = wh1[k]; a1 += hv.x*w.x + hv.y*w.y + hv.z*w.z + hv.w*w.w;
            w = wh2[k]; a2 += hv.x*w.x + hv.y*w.y + hv.z*w.z + hv.w*w.w;
            w = wh3[k]; a3 += hv.x*w.x + hv.y*w.y + hv.z*w.z + hv.w*w.w;
        }
    }

    const float ig = 1.0f / (1.0f + __expf(-a0));
    const float fg = 1.0f / (1.0f + __expf(-a1));
    const float gg = tanhf(a2);
    const float og = 1.0f / (1.0f + __expf(-a3));

    const size_t idx = (size_t)b * HID + j;
    const float c_new = fg * c_prev[idx] + ig * gg;
    const float h_new = og * tanhf(c_new);
    c_out[idx] = c_new;
    h_out[idx] = h_new;
}

__global__ void lstm_finalize(const float* __restrict__ h_fin_src,
                              const float* __restrict__ c_fin_src,
                              float* __restrict__ dst_h,
                              float* __restrict__ dst_c)
{
    const int i = blockIdx.x * blockDim.x + threadIdx.x;
    if (i < BATCH * HID) {
        dst_h[i] = h_fin_src[i];
        dst_c[i] = c_fin_src[i];
    }
}

// No-op probe kernels: which one shows up in next round's rocprof dispatch
// list tells us the ws_size bucket (can we precompute x_gates in ws?).
__global__ void ws_probe_ge_512mb() {}
__global__ void ws_probe_ge_256mb() {}
__global__ void ws_probe_lt_256mb() {}

extern "C" void kernel_launch(void* const* d_in, const int* in_sizes, int n_in,
                              void* d_out, int out_size, void* d_ws, size_t ws_size,
                              hipStream_t stream) {
    const float* input = (const float*)d_in[0];  // [T, B, I]
    const float* h0    = (const float*)d_in[1];  // [B, H]
    const float* c0    = (const float*)d_in[2];  // [B, H]
    const float* W_ih  = (const float*)d_in[3];  // [4H, I]
    const float* W_hh  = (const float*)d_in[4];  // [4H, H]
    const float* b_ih  = (const float*)d_in[5];  // [4H]
    const float* b_hh  = (const float*)d_in[6];  // [4H]

    float* out  = (float*)d_out;
    float* c_ws = (float*)d_ws;                  // B*H floats of scratch for c

    // ws_size probe (no-op kernels, bucket visible in rocprof dispatch names)
    if (ws_size >= 536870912ULL)       hipLaunchKernelGGL(ws_probe_ge_512mb, dim3(1), dim3(64), 0, stream);
    else if (ws_size >= 268435456ULL)  hipLaunchKernelGGL(ws_probe_ge_256mb, dim3(1), dim3(64), 0, stream);
    else                               hipLaunchKernelGGL(ws_probe_lt_256mb, dim3(1), dim3(64), 0, stream);

    const dim3 grid(BATCH * (HID / 256));  // 128 blocks
    const dim3 block(256);

    for (int t = T_STEPS - 1; t >= 0; --t) {
        const float* x_t = input + (size_t)t * BATCH * IN_DIM;
        const float* hp  = (t == T_STEPS - 1) ? h0 : out + (size_t)(t + 1) * BATCH * HID;
        const float* cp  = (t == T_STEPS - 1) ? c0 : c_ws;
        float* ho = out + (size_t)t * BATCH * HID;
        hipLaunchKernelGGL(lstm_step_fused, grid, block, 0, stream,
                           x_t, hp, cp, c_ws, ho, W_ih, W_hh, b_ih, b_hh);
    }

    // h_fin = h after step t=0 (lives at out[0..B*H)); c_fin = c_ws.
    hipLaunchKernelGGL(lstm_finalize, dim3((BATCH * HID + 255) / 256), dim3(256), 0, stream,
                       out, c_ws,
                       out + (size_t)T_STEPS * BATCH * HID,
                       out + (size_t)T_STEPS * BATCH * HID + (size_t)BATCH * HID);
}

// Round 2
// 20047.807 us; speedup vs baseline: 16.1016x; 16.1016x over previous
//
#include <hip/hip_runtime.h>

// ReverseLSTMLayer: T=1024, B=32, I=1024, H=1024, fp32 in/out.
// d_out layout: outputs [T*B*H] | h_fin [B*H] | c_fin [B*H].
//
// Fast path (needs ~160.4 MB ws): split-bf16 (hi/lo) MFMA, 3-pass
// compensation == fp32-class accuracy. Per step: gates[4096,32] =
// Wc[4096,2048] x [x_t; h][2048,32] via v_mfma_f32_16x16x32_bf16,
// fused cell update. 256 blocks x 256 threads, block owns 4 hidden
// units x 4 gates x 32 batches.

constexpr int T_STEPS = 1024;
constexpr int BATCH   = 32;
constexpr int IN_DIM  = 1024;
constexpr int HID     = 1024;
constexpr int KTOT    = IN_DIM + HID;      // 2048

typedef __attribute__((ext_vector_type(8))) short  short8;
typedef __attribute__((ext_vector_type(4))) float  f32x4;

__device__ __forceinline__ unsigned short f2bf(float f) {
    union { float f; unsigned u; } x; x.f = f;
    unsigned r = (x.u + 0x7fffu + ((x.u >> 16) & 1u)) >> 16;
    return (unsigned short)r;
}
__device__ __forceinline__ float bf2f(unsigned short h) {
    union { unsigned u; float f; } x; x.u = ((unsigned)h) << 16;
    return x.f;
}

// ---------------- converters ----------------

// Split fp32 array into bf16 hi + bf16 lo (v = hi + lo), 4 elems/thread.
__global__ void convert_split(const float* __restrict__ src,
                              unsigned short* __restrict__ hi,
                              unsigned short* __restrict__ lo, int n4) {
    for (int i = blockIdx.x * blockDim.x + threadIdx.x; i < n4;
         i += gridDim.x * blockDim.x) {
        const float4 v = ((const float4*)src)[i];
        ushort4 h, l;
        float t;
        h.x = f2bf(v.x); t = v.x - bf2f(h.x); l.x = f2bf(t);
        h.y = f2bf(v.y); t = v.y - bf2f(h.y); l.y = f2bf(t);
        h.z = f2bf(v.z); t = v.z - bf2f(h.z); l.z = f2bf(t);
        h.w = f2bf(v.w); t = v.w - bf2f(h.w); l.w = f2bf(t);
        ((ushort4*)hi)[i] = h;
        ((ushort4*)lo)[i] = l;
    }
}

// Combine W_ih|W_hh into Wc[4096][2048] and split hi/lo.
__global__ void convert_W(const float* __restrict__ W_ih,
                          const float* __restrict__ W_hh,
                          unsigned short* __restrict__ Whi,
                          unsigned short* __restrict__ Wlo) {
    const int n4 = 4096 * KTOT / 4;   // 2,097,152
    for (int i = blockIdx.x * blockDim.x + threadIdx.x; i < n4;
         i += gridDim.x * blockDim.x) {
        const int flat = i * 4;
        const int r = flat >> 11;          // row 0..4095
        const int k = flat & (KTOT - 1);   // 0..2047, 4-aligned
        const float4 v = (k < IN_DIM)
            ? *(const float4*)(W_ih + (size_t)r * IN_DIM + k)
            : *(const float4*)(W_hh + (size_t)r * HID + (k - IN_DIM));
        ushort4 h, l;
        float t;
        h.x = f2bf(v.x); t = v.x - bf2f(h.x); l.x = f2bf(t);
        h.y = f2bf(v.y); t = v.y - bf2f(h.y); l.y = f2bf(t);
        h.z = f2bf(v.z); t = v.z - bf2f(h.z); l.z = f2bf(t);
        h.w = f2bf(v.w); t = v.w - bf2f(h.w); l.w = f2bf(t);
        ((ushort4*)Whi)[i] = h;
        ((ushort4*)Wlo)[i] = l;
    }
}

// h0 split, c0 copy, bias combine.
__global__ void prep_state(const float* __restrict__ h0,
                           const float* __restrict__ c0,
                           const float* __restrict__ b_ih,
                           const float* __restrict__ b_hh,
                           unsigned short* __restrict__ h_hi,
                           unsigned short* __restrict__ h_lo,
                           float* __restrict__ c,
                           float* __restrict__ bias) {
    const int i = blockIdx.x * blockDim.x + threadIdx.x;
    if (i < BATCH * HID) {
        const float v = h0[i];
        const unsigned short hh = f2bf(v);
        h_hi[i] = hh;
        h_lo[i] = f2bf(v - bf2f(hh));
        c[i] = c0[i];
    }
    if (i < 4 * HID) bias[i] = b_ih[i] + b_hh[i];
}

// ---------------- fused MFMA step ----------------
// Block: j0 = blockIdx.x*4. Owns W rows {g*1024 + j0 + jj : g in 0..3, jj in 0..3}
// (m = g*4+jj), all 32 batches. a = [x_t; h] staged in LDS per 512-K chunk as
// bf16 hi/lo. 4 waves split the 16 K-steps of each chunk. 3-pass split-bf16.
#define APAD 520   // 512 + 8 pad: row stride 1040 B = 16-aligned, 2-way banks

__global__ __launch_bounds__(256) void lstm_step_mfma(
    const unsigned short* __restrict__ x_hi_t,  // [32][1024] slice at step t
    const unsigned short* __restrict__ x_lo_t,
    const unsigned short* __restrict__ hin_hi,  // [32][1024]
    const unsigned short* __restrict__ hin_lo,
    unsigned short* __restrict__ hout_hi,
    unsigned short* __restrict__ hout_lo,
    const unsigned short* __restrict__ Whi,     // [4096][2048]
    const unsigned short* __restrict__ Wlo,
    const float* __restrict__ bias,             // [4096]
    float* __restrict__ c,                      // [32][1024]
    float* __restrict__ h_out)                  // out + t*B*H, [32][1024]
{
    __shared__ unsigned short a_hi[BATCH][APAD];
    __shared__ unsigned short a_lo[BATCH][APAD];
    __shared__ float red[8 * 256];              // [wave*2+mtile][row16][col16]

    const int tid  = threadIdx.x;
    const int wave = tid >> 6;
    const int lane = tid & 63;
    const int j0   = blockIdx.x << 2;

    // A-frag addressing: lane covers W row rowA, k-group kg (8 contiguous k)
    const int m    = lane & 15;
    const int kg   = (lane >> 4) << 3;                    // 0,8,16,24
    const int rowA = ((m >> 2) << 10) + j0 + (m & 3);     // g*1024 + j0 + jj
    const size_t wbase = (size_t)rowA * KTOT;

    f32x4 acc0 = {0.f, 0.f, 0.f, 0.f};   // batches 0-15
    f32x4 acc1 = {0.f, 0.f, 0.f, 0.f};   // batches 16-31

    for (int chunk = 0; chunk < 4; ++chunk) {
        const unsigned short* shi;
        const unsigned short* slo;
        int kbase;
        if (chunk < 2) { shi = x_hi_t; slo = x_lo_t; kbase = chunk * 512; }
        else           { shi = hin_hi; slo = hin_lo; kbase = (chunk - 2) * 512; }

        __syncthreads();   // previous chunk's LDS reads complete
        for (int i = tid; i < BATCH * 64; i += 256) {
            const int b  = i >> 6;
            const int kk = (i & 63) << 3;
            *(uint4*)&a_hi[b][kk] = *(const uint4*)(shi + (size_t)b * 1024 + kbase + kk);
            *(uint4*)&a_lo[b][kk] = *(const uint4*)(slo + (size_t)b * 1024 + kbase + kk);
        }
        __syncthreads();

        const int kchunk = chunk * 512;
        #pragma unroll
        for (int ks = 0; ks < 4; ++ks) {
            const int kcs = ((wave << 2) + ks) << 5;      // within-chunk k, 0..480
            const int kabs = kchunk + kcs + kg;
            const short8 whi = *(const short8*)(Whi + wbase + kabs);
            const short8 wlo = *(const short8*)(Wlo + wbase + kabs);
            const short8 bh0 = *(const short8*)&a_hi[lane & 15][kcs + kg];
            const short8 bh1 = *(const short8*)&a_hi[16 + (lane & 15)][kcs + kg];
            const short8 bl0 = *(const short8*)&a_lo[lane & 15][kcs + kg];
            const short8 bl1 = *(const short8*)&a_lo[16 + (lane & 15)][kcs + kg];
            acc0 = __builtin_amdgcn_mfma_f32_16x16x32_bf16(whi, bh0, acc0, 0, 0, 0);
            acc0 = __builtin_amdgcn_mfma_f32_16x16x32_bf16(whi, bl0, acc0, 0, 0, 0);
            acc0 = __builtin_amdgcn_mfma_f32_16x16x32_bf16(wlo, bh0, acc0, 0, 0, 0);
            acc1 = __builtin_amdgcn_mfma_f32_16x16x32_bf16(whi, bh1, acc1, 0, 0, 0);
            acc1 = __builtin_amdgcn_mfma_f32_16x16x32_bf16(whi, bl1, acc1, 0, 0, 0);
            acc1 = __builtin_amdgcn_mfma_f32_16x16x32_bf16(wlo, bh1, acc1, 0, 0, 0);
        }
    }

    // Cross-wave reduce via LDS. C/D layout (m89-verified): col=lane&15,
    // row=4*(lane>>4)+reg.
    {
        const int arow = (lane >> 4) << 2;
        const int acol = lane & 15;
        #pragma unroll
        for (int r = 0; r < 4; ++r) {
            red[(wave * 2 + 0) * 256 + (arow + r) * 16 + acol] = acc0[r];
            red[(wave * 2 + 1) * 256 + (arow + r) * 16 + acol] = acc1[r];
        }
    }
    __syncthreads();

    if (tid < 128) {
        const int jj = tid & 3;
        const int b  = tid >> 2;
        const int mt = b >> 4;
        const int col = b & 15;
        float val[4];
        #pragma unroll
        for (int g = 0; g < 4; ++g) {
            const int rr = (g * 4 + jj) * 16 + col;
            float s = red[(0 * 2 + mt) * 256 + rr] + red[(1 * 2 + mt) * 256 + rr]
                    + red[(2 * 2 + mt) * 256 + rr] + red[(3 * 2 + mt) * 256 + rr];
            val[g] = s + bias[g * HID + j0 + jj];
        }
        const float ig = 1.0f / (1.0f + __expf(-val[0]));
        const float fg = 1.0f / (1.0f + __expf(-val[1]));
        const float gg = tanhf(val[2]);
        const float og = 1.0f / (1.0f + __expf(-val[3]));
        const int idx = b * HID + j0 + jj;
        const float c_new = fg * c[idx] + ig * gg;
        c[idx] = c_new;
        const float h_new = og * tanhf(c_new);
        h_out[idx] = h_new;
        const unsigned short hh = f2bf(h_new);
        hout_hi[idx] = hh;
        hout_lo[idx] = f2bf(h_new - bf2f(hh));
    }
}

__global__ void lstm_finalize(const float* __restrict__ h_fin_src,
                              const float* __restrict__ c_fin_src,
                              float* __restrict__ dst_h,
                              float* __restrict__ dst_c) {
    const int i = blockIdx.x * blockDim.x + threadIdx.x;
    if (i < BATCH * HID) { dst_h[i] = h_fin_src[i]; dst_c[i] = c_fin_src[i]; }
}

// ---------------- fallback (round-1, known-good, slow) ----------------
__global__ __launch_bounds__(256) void lstm_step_fused(
    const float* __restrict__ x_t, const float* __restrict__ h_prev,
    const float* __restrict__ c_prev, float* __restrict__ c_out,
    float* __restrict__ h_out, const float* __restrict__ W_ih,
    const float* __restrict__ W_hh, const float* __restrict__ b_ih,
    const float* __restrict__ b_hh) {
    __shared__ float xs[IN_DIM];
    __shared__ float hs[HID];
    const int tid = threadIdx.x;
    const int b   = blockIdx.x >> 2;
    const int j   = ((blockIdx.x & 3) << 8) | tid;
    ((float4*)xs)[tid] = ((const float4*)(x_t    + (size_t)b * IN_DIM))[tid];
    ((float4*)hs)[tid] = ((const float4*)(h_prev + (size_t)b * HID))[tid];
    __syncthreads();
    float a0 = b_ih[j] + b_hh[j];
    float a1 = b_ih[HID + j] + b_hh[HID + j];
    float a2 = b_ih[2*HID + j] + b_hh[2*HID + j];
    float a3 = b_ih[3*HID + j] + b_hh[3*HID + j];
    {
        const float4* wi0 = (const float4*)(W_ih + (size_t)(0*HID + j) * IN_DIM);
        const float4* wi1 = (const float4*)(W_ih + (size_t)(1*HID + j) * IN_DIM);
        const float4* wi2 = (const float4*)(W_ih + (size_t)(2*HID + j) * IN_DIM);
        const float4* wi3 = (const float4*)(W_ih + (size_t)(3*HID + j) * IN_DIM);
        const float4* xs4 = (const float4*)xs;
        #pragma unroll 4
        for (int k = 0; k < IN_DIM / 4; ++k) {
            const float4 xv = xs4[k]; float4 w;
            w = wi0[k]; a0 += xv.x*w.x + xv.y*w.y + xv.z*w.z + xv.w*w.w;
            w = wi1[k]; a1 += xv.x*w.x + xv.y*w.y + xv.z*w.z + xv.w*w.w;
            w = wi2[k]; a2 += xv.x*w.x + xv.y*w.y + xv.z*w.z + xv.w*w.w;
            w = wi3[k]; a3 += xv.x*w.x + xv.y*w.y + xv.z*w.z + xv.w*w.w;
        }
    }
    {
        const float4* wh0 = (const float4*)(W_hh + (size_t)(0*HID + j) * HID);
        const float4* wh1 = (const float4*)(W_hh + (size_t)(1*HID + j) * HID);
        const float4* wh2 = (const float4*)(W_hh + (size_t)(2*HID + j) * HID);
        const float4* wh3 = (const float4*)(W_hh + (size_t)(3*HID + j) * HID);
        const float4* hs4 = (const float4*)hs;
        #pragma unroll 4
        for (int k = 0; k < HID / 4; ++k) {
            const float4 hv = hs4[k]; float4 w;
            w = wh0[k]; a0 += hv.x*w.x + hv.y*w.y + hv.z*w.z + hv.w*w.w;
            w = wh1[k]; a1 += hv.x*w.x + hv.y*w.y + hv.z*w.z + hv.w*w.w;
            w = wh2[k]; a2 += hv.x*w.x + hv.y*w.y + hv.z*w.z + hv.w*w.w;
            w = wh3[k]; a3 += hv.x*w.x + hv.y*w.y + hv.z*w.z + hv.w*w.w;
        }
    }
    const float ig = 1.0f / (1.0f + __expf(-a0));
    const float fg = 1.0f / (1.0f + __expf(-a1));
    const float gg = tanhf(a2);
    const float og = 1.0f / (1.0f + __expf(-a3));
    const size_t idx = (size_t)b * HID + j;
    const float c_new = fg * c_prev[idx] + ig * gg;
    c_out[idx] = c_new;
    h_out[idx] = og * tanhf(c_new);
}

// ---------------- host ----------------

extern "C" void kernel_launch(void* const* d_in, const int* in_sizes, int n_in,
                              void* d_out, int out_size, void* d_ws, size_t ws_size,
                              hipStream_t stream) {
    const float* input = (const float*)d_in[0];
    const float* h0    = (const float*)d_in[1];
    const float* c0    = (const float*)d_in[2];
    const float* W_ih  = (const float*)d_in[3];
    const float* W_hh  = (const float*)d_in[4];
    const float* b_ih  = (const float*)d_in[5];
    const float* b_hh  = (const float*)d_in[6];
    float* out = (float*)d_out;

    // ws carve-up (fast path)
    const size_t SZ_XHI  = (size_t)T_STEPS * BATCH * IN_DIM * 2;   // 64 MB
    const size_t SZ_W    = (size_t)4096 * KTOT * 2;                // 16 MB
    const size_t OFF_XHI  = 0;
    const size_t OFF_XLO  = OFF_XHI + SZ_XHI;
    const size_t OFF_WHI  = OFF_XLO + SZ_XHI;
    const size_t OFF_WLO  = OFF_WHI + SZ_W;
    const size_t OFF_BIAS = OFF_WLO + SZ_W;                        // 16 KB
    const size_t OFF_H    = OFF_BIAS + 16384;                      // 4x64 KB
    const size_t OFF_C    = OFF_H + 4 * 65536;                     // 128 KB
    const size_t NEED     = OFF_C + 131072;

    if (ws_size >= NEED) {
        unsigned char* w = (unsigned char*)d_ws;
        unsigned short* x_hi = (unsigned short*)(w + OFF_XHI);
        unsigned short* x_lo = (unsigned short*)(w + OFF_XLO);
        unsigned short* Whi  = (unsigned short*)(w + OFF_WHI);
        unsigned short* Wlo  = (unsigned short*)(w + OFF_WLO);
        float* bias = (float*)(w + OFF_BIAS);
        unsigned short* hhi[2] = {(unsigned short*)(w + OFF_H),
                                  (unsigned short*)(w + OFF_H + 131072)};
        unsigned short* hlo[2] = {(unsigned short*)(w + OFF_H + 65536),
                                  (unsigned short*)(w + OFF_H + 196608)};
        float* c = (float*)(w + OFF_C);

        hipLaunchKernelGGL(convert_split, dim3(4096), dim3(256), 0, stream,
                           input, x_hi, x_lo, T_STEPS * BATCH * IN_DIM / 4);
        hipLaunchKernelGGL(convert_W, dim3(2048), dim3(256), 0, stream,
                           W_ih, W_hh, Whi, Wlo);
        hipLaunchKernelGGL(prep_state, dim3(128), dim3(256), 0, stream,
                           h0, c0, b_ih, b_hh, hhi[0], hlo[0], c, bias);

        for (int i = 0; i < T_STEPS; ++i) {
            const int t = T_STEPS - 1 - i;
            const size_t xoff = (size_t)t * BATCH * IN_DIM;
            hipLaunchKernelGGL(lstm_step_mfma, dim3(256), dim3(256), 0, stream,
                               x_hi + xoff, x_lo + xoff,
                               hhi[i & 1], hlo[i & 1],
                               hhi[(i + 1) & 1], hlo[(i + 1) & 1],
                               Whi, Wlo, bias, c,
                               out + (size_t)t * BATCH * HID);
        }
        hipLaunchKernelGGL(lstm_finalize, dim3(128), dim3(256), 0, stream,
                           out, c,
                           out + (size_t)T_STEPS * BATCH * HID,
                           out + (size_t)T_STEPS * BATCH * HID + BATCH * HID);
    } else {
        // fallback: round-1 path (c scratch only)
        float* c_ws = (float*)d_ws;
        for (int t = T_STEPS - 1; t >= 0; --t) {
            const float* x_t = input + (size_t)t * BATCH * IN_DIM;
            const float* hp  = (t == T_STEPS - 1) ? h0 : out + (size_t)(t + 1) * BATCH * HID;
            const float* cp  = (t == T_STEPS - 1) ? c0 : c_ws;
            hipLaunchKernelGGL(lstm_step_fused, dim3(128), dim3(256), 0, stream,
                               x_t, hp, cp, c_ws, out + (size_t)t * BATCH * HID,
                               W_ih, W_hh, b_ih, b_hh);
        }
        hipLaunchKernelGGL(lstm_finalize, dim3(128), dim3(256), 0, stream,
                           out, c_ws,
                           out + (size_t)T_STEPS * BATCH * HID,
                           out + (size_t)T_STEPS * BATCH * HID + BATCH * HID);
    }
}